// Round 1
// baseline (26004.730 us; speedup 1.0000x reference)
//
#include <hip/hip_runtime.h>
#include <hip/hip_bf16.h>

// Problem constants (from reference): B=2, S=2048, dim=4096, H=32, HKV=8, HD=128
#define BATCH 2
#define SEQ   2048
#define DIM   4096
#define KVDIM 1024
#define NH    32
#define NKVH  8
#define HD    128

// ---------------------------------------------------------------------------
// SGEMM: C[M,N] = A[M,K] @ B[K,N], row-major, fp32.
// BM=BN=128, BK=16, 256 threads, 8x8 per thread. M%128==0, N%128==0, K%16==0.
// ---------------------------------------------------------------------------
__global__ __launch_bounds__(256) void sgemm_kernel(
    const float* __restrict__ A, const float* __restrict__ B,
    float* __restrict__ C, int M, int N, int K) {
  __shared__ float As[16][132];  // stored transposed: As[k][m], +4 pad
  __shared__ float Bs[16][132];  // Bs[k][n], +4 pad

  const int t  = threadIdx.x;
  const int tx = t & 15;         // n-dir
  const int ty = t >> 4;         // m-dir
  const int bm = blockIdx.x * 128;
  const int bn = blockIdx.y * 128;

  // A tile: 128x16 = 512 float4 (4 per row). thread t -> f4 ids t, t+256.
  const int ar = t >> 2;          // 0..63 (and +64)
  const int ac = (t & 3) * 4;     // 0,4,8,12
  // B tile: 16x128 = 512 float4 (32 per row). thread t -> f4 ids t, t+256.
  const int br = t >> 5;          // 0..7 (and +8)
  const int bc = (t & 31) * 4;    // 0..124

  float acc[8][8] = {};

  for (int kt = 0; kt < K; kt += 16) {
    const float4 a0 = *(const float4*)&A[(long)(bm + ar)      * K + kt + ac];
    const float4 a1 = *(const float4*)&A[(long)(bm + ar + 64) * K + kt + ac];
    const float4 b0 = *(const float4*)&B[(long)(kt + br)     * N + bn + bc];
    const float4 b1 = *(const float4*)&B[(long)(kt + br + 8) * N + bn + bc];

    __syncthreads();  // previous compute done before overwriting LDS

    As[ac + 0][ar] = a0.x;  As[ac + 1][ar] = a0.y;
    As[ac + 2][ar] = a0.z;  As[ac + 3][ar] = a0.w;
    As[ac + 0][ar + 64] = a1.x;  As[ac + 1][ar + 64] = a1.y;
    As[ac + 2][ar + 64] = a1.z;  As[ac + 3][ar + 64] = a1.w;
    *(float4*)&Bs[br][bc]     = b0;
    *(float4*)&Bs[br + 8][bc] = b1;

    __syncthreads();

#pragma unroll
    for (int k = 0; k < 16; ++k) {
      float ar8[8], br8[8];
      *(float4*)&ar8[0] = *(const float4*)&As[k][ty * 8];
      *(float4*)&ar8[4] = *(const float4*)&As[k][ty * 8 + 4];
      *(float4*)&br8[0] = *(const float4*)&Bs[k][tx * 8];
      *(float4*)&br8[4] = *(const float4*)&Bs[k][tx * 8 + 4];
#pragma unroll
      for (int i = 0; i < 8; ++i)
#pragma unroll
        for (int j = 0; j < 8; ++j)
          acc[i][j] = fmaf(ar8[i], br8[j], acc[i][j]);
    }
  }

#pragma unroll
  for (int i = 0; i < 8; ++i) {
    float* cp = &C[(long)(bm + ty * 8 + i) * N + bn + tx * 8];
    *(float4*)(cp + 0) = make_float4(acc[i][0], acc[i][1], acc[i][2], acc[i][3]);
    *(float4*)(cp + 4) = make_float4(acc[i][4], acc[i][5], acc[i][6], acc[i][7]);
  }
}

// ---------------------------------------------------------------------------
// Attention: one wave per (b, h, q-row). 4 waves / block.
// Q,Ctx layout: [B*S, NH*HD]; K,V layout: [B*S, NKVH*HD].
// ---------------------------------------------------------------------------
__global__ __launch_bounds__(256) void attn_kernel(
    const float* __restrict__ Q, const float* __restrict__ Kb,
    const float* __restrict__ Vb, float* __restrict__ O) {
  __shared__ float p_lds[4][SEQ];   // 32 KB: scores -> probabilities per wave
  __shared__ float q_lds[4][HD];    // 2 KB

  const int t    = threadIdx.x;
  const int wid  = t >> 6;
  const int lane = t & 63;

  const long wg  = (long)blockIdx.x * 4 + wid;   // 0 .. B*NH*SEQ-1
  const int  b   = (int)(wg >> 16);              // / (NH*SEQ) = / 65536
  const int  rem = (int)(wg & 65535);
  const int  h   = rem >> 11;                    // / SEQ
  const int  qs  = rem & (SEQ - 1);
  const int  hkv = h >> 2;                       // n_rep = 4, repeat_interleave

  const float* qp = Q + ((long)(b * SEQ + qs) * NH + h) * HD;
  ((float2*)q_lds[wid])[lane] = ((const float2*)qp)[lane];
  __syncthreads();

  const float* kbase = Kb + ((long)b * SEQ * NKVH + hkv) * HD;
  const float* vbase = Vb + ((long)b * SEQ * NKVH + hkv) * HD;

  // Phase 1: scores for keys lane, lane+64, ...
  const float scale = 0.08838834764831845f;  // 1/sqrt(128)
  float m = -INFINITY;
  for (int kk = lane; kk < SEQ; kk += 64) {
    const float4* kr = (const float4*)(kbase + (long)kk * KVDIM);
    float dot = 0.f;
#pragma unroll
    for (int d4 = 0; d4 < HD / 4; ++d4) {
      const float4 kv = kr[d4];
      const float4 qv = ((const float4*)q_lds[wid])[d4];
      dot = fmaf(kv.x, qv.x, dot);
      dot = fmaf(kv.y, qv.y, dot);
      dot = fmaf(kv.z, qv.z, dot);
      dot = fmaf(kv.w, qv.w, dot);
    }
    dot *= scale;
    p_lds[wid][kk] = dot;
    m = fmaxf(m, dot);
  }
#pragma unroll
  for (int off = 32; off; off >>= 1) m = fmaxf(m, __shfl_xor(m, off));

  // Phase 2: exp + sum
  float sum = 0.f;
  for (int kk = lane; kk < SEQ; kk += 64) {
    const float e = __expf(p_lds[wid][kk] - m);
    p_lds[wid][kk] = e;
    sum += e;
  }
#pragma unroll
  for (int off = 32; off; off >>= 1) sum += __shfl_xor(sum, off);
  const float inv = 1.0f / sum;

  // Phase 3: PV. Each lane owns 2 output dims (float2), coalesced V reads.
  const float* vp = vbase + lane * 2;
  float2 acc = make_float2(0.f, 0.f);
  for (int kk = 0; kk < SEQ; kk += 4) {
    const float4 p4 = *(const float4*)&p_lds[wid][kk];
    const float2 v0 = *(const float2*)(vp + (long)(kk + 0) * KVDIM);
    const float2 v1 = *(const float2*)(vp + (long)(kk + 1) * KVDIM);
    const float2 v2 = *(const float2*)(vp + (long)(kk + 2) * KVDIM);
    const float2 v3 = *(const float2*)(vp + (long)(kk + 3) * KVDIM);
    acc.x = fmaf(p4.x, v0.x, acc.x); acc.y = fmaf(p4.x, v0.y, acc.y);
    acc.x = fmaf(p4.y, v1.x, acc.x); acc.y = fmaf(p4.y, v1.y, acc.y);
    acc.x = fmaf(p4.z, v2.x, acc.x); acc.y = fmaf(p4.z, v2.y, acc.y);
    acc.x = fmaf(p4.w, v3.x, acc.x); acc.y = fmaf(p4.w, v3.y, acc.y);
  }
  float* op = O + ((long)(b * SEQ + qs) * NH + h) * HD + lane * 2;
  *(float2*)op = make_float2(acc.x * inv, acc.y * inv);
}

// ---------------------------------------------------------------------------
extern "C" void kernel_launch(void* const* d_in, const int* in_sizes, int n_in,
                              void* d_out, int out_size, void* d_ws, size_t ws_size,
                              hipStream_t stream) {
  const float* x  = (const float*)d_in[0];
  const float* wq = (const float*)d_in[1];
  const float* wk = (const float*)d_in[2];
  const float* wv = (const float*)d_in[3];
  const float* wo = (const float*)d_in[4];
  float* out = (float*)d_out;

  const long T = (long)BATCH * SEQ;  // 4096 tokens

  float* Q   = (float*)d_ws;                 // T x DIM   (64 MB)
  float* Kb  = Q   + T * DIM;                // T x KVDIM (16 MB)
  float* Vb  = Kb  + T * KVDIM;              // T x KVDIM (16 MB)
  float* Ctx = Vb  + T * KVDIM;              // T x DIM   (64 MB)

  dim3 blk(256);
  // Projections
  sgemm_kernel<<<dim3(T / 128, DIM / 128),   blk, 0, stream>>>(x, wq, Q,  (int)T, DIM,   DIM);
  sgemm_kernel<<<dim3(T / 128, KVDIM / 128), blk, 0, stream>>>(x, wk, Kb, (int)T, KVDIM, DIM);
  sgemm_kernel<<<dim3(T / 128, KVDIM / 128), blk, 0, stream>>>(x, wv, Vb, (int)T, KVDIM, DIM);
  // Attention
  attn_kernel<<<dim3((BATCH * NH * SEQ) / 4), blk, 0, stream>>>(Q, Kb, Vb, Ctx);
  // Output projection
  sgemm_kernel<<<dim3(T / 128, DIM / 128),   blk, 0, stream>>>(Ctx, wo, out, (int)T, DIM, DIM);
}

// Round 2
// 7136.566 us; speedup vs baseline: 3.6439x; 3.6439x over previous
//
#include <hip/hip_runtime.h>
#include <hip/hip_bf16.h>

// Problem constants (from reference): B=2, S=2048, dim=4096, H=32, HKV=8, HD=128
#define BATCH 2
#define SEQ   2048
#define DIM   4096
#define KVDIM 1024
#define NH    32
#define NKVH  8
#define HD    128

#define QT 64   // q rows per block
#define KT 32   // keys per tile

// ---------------------------------------------------------------------------
// SGEMM: C[M,N] = A[M,K] @ B[K,N], row-major, fp32.
// BM=BN=128, BK=16, 256 threads, 8x8 per thread. M%128==0, N%128==0, K%16==0.
// ---------------------------------------------------------------------------
__global__ __launch_bounds__(256) void sgemm_kernel(
    const float* __restrict__ A, const float* __restrict__ B,
    float* __restrict__ C, int M, int N, int K) {
  __shared__ float As[16][132];  // stored transposed: As[k][m], +4 pad
  __shared__ float Bs[16][132];  // Bs[k][n], +4 pad

  const int t  = threadIdx.x;
  const int tx = t & 15;         // n-dir
  const int ty = t >> 4;         // m-dir
  const int bm = blockIdx.x * 128;
  const int bn = blockIdx.y * 128;

  const int ar = t >> 2;          // 0..63 (and +64)
  const int ac = (t & 3) * 4;     // 0,4,8,12
  const int br = t >> 5;          // 0..7 (and +8)
  const int bc = (t & 31) * 4;    // 0..124

  float acc[8][8] = {};

  for (int kt = 0; kt < K; kt += 16) {
    const float4 a0 = *(const float4*)&A[(long)(bm + ar)      * K + kt + ac];
    const float4 a1 = *(const float4*)&A[(long)(bm + ar + 64) * K + kt + ac];
    const float4 b0 = *(const float4*)&B[(long)(kt + br)     * N + bn + bc];
    const float4 b1 = *(const float4*)&B[(long)(kt + br + 8) * N + bn + bc];

    __syncthreads();

    As[ac + 0][ar] = a0.x;  As[ac + 1][ar] = a0.y;
    As[ac + 2][ar] = a0.z;  As[ac + 3][ar] = a0.w;
    As[ac + 0][ar + 64] = a1.x;  As[ac + 1][ar + 64] = a1.y;
    As[ac + 2][ar + 64] = a1.z;  As[ac + 3][ar + 64] = a1.w;
    *(float4*)&Bs[br][bc]     = b0;
    *(float4*)&Bs[br + 8][bc] = b1;

    __syncthreads();

#pragma unroll
    for (int k = 0; k < 16; ++k) {
      float ar8[8], br8[8];
      *(float4*)&ar8[0] = *(const float4*)&As[k][ty * 8];
      *(float4*)&ar8[4] = *(const float4*)&As[k][ty * 8 + 4];
      *(float4*)&br8[0] = *(const float4*)&Bs[k][tx * 8];
      *(float4*)&br8[4] = *(const float4*)&Bs[k][tx * 8 + 4];
#pragma unroll
      for (int i = 0; i < 8; ++i)
#pragma unroll
        for (int j = 0; j < 8; ++j)
          acc[i][j] = fmaf(ar8[i], br8[j], acc[i][j]);
    }
  }

#pragma unroll
  for (int i = 0; i < 8; ++i) {
    float* cp = &C[(long)(bm + ty * 8 + i) * N + bn + tx * 8];
    *(float4*)(cp + 0) = make_float4(acc[i][0], acc[i][1], acc[i][2], acc[i][3]);
    *(float4*)(cp + 4) = make_float4(acc[i][4], acc[i][5], acc[i][6], acc[i][7]);
  }
}

// ---------------------------------------------------------------------------
// Flash attention, fp32. Block = 256 threads (4 waves) handles one
// (b, h, 64-row q-tile). K-tiles of 32 streamed through LDS with register
// prefetch. Online softmax. P^T staged in the retired K LDS region.
// LDS: Q 32KB + K/P 16KB + V 16KB = 64KB -> 2 blocks/CU.
// ---------------------------------------------------------------------------
__device__ __forceinline__ void fma4(float4& a, float s, const float4& v) {
  a.x = fmaf(s, v.x, a.x); a.y = fmaf(s, v.y, a.y);
  a.z = fmaf(s, v.z, a.z); a.w = fmaf(s, v.w, a.w);
}
__device__ __forceinline__ void mul4(float4& a, float s) {
  a.x *= s; a.y *= s; a.z *= s; a.w *= s;
}

__global__ __launch_bounds__(256) void attn_kernel(
    const float* __restrict__ Q, const float* __restrict__ Kb,
    const float* __restrict__ Vb, float* __restrict__ O) {
  __shared__ float4 Qs[QT * 32];    // [r][c4 ^ (r&7)]          32 KB
  __shared__ float4 KPs[KT * 32];   // K: [k][c4 ^ ((k>>1)&7)]  16 KB; later P^T[32][68] floats
  __shared__ float4 Vs[KT * 32];    // [k][c4 ^ ((k>>1)&7)]     16 KB

  float* Pt = (float*)KPs;          // P^T row stride 68 floats (17 f4)

  const int t  = threadIdx.x;
  const int qg = t >> 4;            // 0..15 -> q rows qg*4+i
  const int kg = t & 15;            // S phase: k cols kg*2+jj
  const int dg = t & 15;            // PV phase: d cols dg*8

  const int tile = blockIdx.x & 31;            // q-tile within head
  const int h    = (blockIdx.x >> 5) & 31;
  const int b    = blockIdx.x >> 10;
  const int bq   = tile * QT;
  const int hkv  = h >> 2;                     // repeat_interleave, n_rep=4

  const float4* Qg = (const float4*)(Q + ((long)(b * SEQ + bq) * NH + h) * HD);
  const float4* Kg = (const float4*)(Kb + (long)b * SEQ * KVDIM + hkv * HD);
  const float4* Vg = (const float4*)(Vb + (long)b * SEQ * KVDIM + hkv * HD);

  // ---- stage Q tile (swizzled) ----
  {
    const int r  = t >> 2;           // 0..63
    const int c0 = t & 3;            // +4j
#pragma unroll
    for (int j = 0; j < 8; ++j) {
      const int c4 = c0 + 4 * j;
      Qs[r * 32 + (c4 ^ (r & 7))] = Qg[(long)r * (DIM / 4) + c4];
    }
  }

  // ---- prefetch K/V tile 0 into registers ----
  const int krow = t >> 3;           // 0..31
  const int kc0  = t & 7;            // +8j
  float4 kreg[4], vreg[4];
#pragma unroll
  for (int j = 0; j < 4; ++j) {
    kreg[j] = Kg[(long)krow * (KVDIM / 4) + kc0 + 8 * j];
    vreg[j] = Vg[(long)krow * (KVDIM / 4) + kc0 + 8 * j];
  }

  float4 o4[4][2] = {};
  float m[4] = {-INFINITY, -INFINITY, -INFINITY, -INFINITY};
  float l[4] = {0.f, 0.f, 0.f, 0.f};

  const int NT = SEQ / KT;           // 64
  for (int kt = 0; kt < NT; ++kt) {
    // write prefetched K/V into LDS (swizzled)
#pragma unroll
    for (int j = 0; j < 4; ++j) {
      const int c4 = kc0 + 8 * j;
      const int ph = c4 ^ ((krow >> 1) & 7);
      KPs[krow * 32 + ph] = kreg[j];
      Vs [krow * 32 + ph] = vreg[j];
    }
    __syncthreads();   // #1: tile ready

    // prefetch next tile (hidden under S + PV compute)
    if (kt + 1 < NT) {
      const long base = (long)((kt + 1) * KT + krow) * (KVDIM / 4);
#pragma unroll
      for (int j = 0; j < 4; ++j) {
        kreg[j] = Kg[base + kc0 + 8 * j];
        vreg[j] = Vg[base + kc0 + 8 * j];
      }
    }

    // ---- S = Q K^T : per-thread 4 q x 2 k ----
    float s[4][2] = {};
    const int k0 = kg * 2, k1 = k0 + 1;
    const int fk = (k0 >> 1) & 7;    // same for k0,k1
#pragma unroll
    for (int d4 = 0; d4 < 32; ++d4) {
      const float4 kv0 = KPs[k0 * 32 + (d4 ^ fk)];
      const float4 kv1 = KPs[k1 * 32 + (d4 ^ fk)];
#pragma unroll
      for (int i = 0; i < 4; ++i) {
        const int r = qg * 4 + i;
        const float4 qv = Qs[r * 32 + (d4 ^ (r & 7))];
        s[i][0] += qv.x * kv0.x + qv.y * kv0.y + qv.z * kv0.z + qv.w * kv0.w;
        s[i][1] += qv.x * kv1.x + qv.y * kv1.y + qv.z * kv1.z + qv.w * kv1.w;
      }
    }

    // ---- online softmax (16-lane groups share a q-row set) ----
    const float scale = 0.08838834764831845f;  // 1/sqrt(128)
    float pr[4][2];
#pragma unroll
    for (int i = 0; i < 4; ++i) {
      const float s0 = s[i][0] * scale, s1 = s[i][1] * scale;
      float mt = fmaxf(s0, s1);
      mt = fmaxf(mt, __shfl_xor(mt, 1));
      mt = fmaxf(mt, __shfl_xor(mt, 2));
      mt = fmaxf(mt, __shfl_xor(mt, 4));
      mt = fmaxf(mt, __shfl_xor(mt, 8));
      const float mn  = fmaxf(m[i], mt);
      const float cor = __expf(m[i] - mn);
      m[i] = mn;
      const float p0 = __expf(s0 - mn), p1 = __expf(s1 - mn);
      pr[i][0] = p0; pr[i][1] = p1;
      float rs = p0 + p1;
      rs += __shfl_xor(rs, 1);
      rs += __shfl_xor(rs, 2);
      rs += __shfl_xor(rs, 4);
      rs += __shfl_xor(rs, 8);
      l[i] = l[i] * cor + rs;
      mul4(o4[i][0], cor);
      mul4(o4[i][1], cor);
    }
    __syncthreads();   // #2: all K reads done, safe to overwrite with P^T

    // write P^T [32 k][68-stride q]
#pragma unroll
    for (int i = 0; i < 4; ++i) {
      Pt[k0 * 68 + qg * 4 + i] = pr[i][0];
      Pt[k1 * 68 + qg * 4 + i] = pr[i][1];
    }
    __syncthreads();   // #3: P^T visible

    // ---- O += P V : per-thread 4 q x 8 d ----
#pragma unroll 8
    for (int k = 0; k < KT; ++k) {
      const float4 p4 = ((const float4*)Pt)[k * 17 + qg];
      const int fv = (k >> 1) & 7;
      const float4 v0 = Vs[k * 32 + ((dg * 2)     ^ fv)];
      const float4 v1 = Vs[k * 32 + ((dg * 2 + 1) ^ fv)];
      fma4(o4[0][0], p4.x, v0); fma4(o4[0][1], p4.x, v1);
      fma4(o4[1][0], p4.y, v0); fma4(o4[1][1], p4.y, v1);
      fma4(o4[2][0], p4.z, v0); fma4(o4[2][1], p4.z, v1);
      fma4(o4[3][0], p4.w, v0); fma4(o4[3][1], p4.w, v1);
    }
    __syncthreads();   // #4: PV reads done before next tile's LDS writes
  }

  // ---- epilogue: normalize + store ----
#pragma unroll
  for (int i = 0; i < 4; ++i) {
    const float inv = 1.0f / l[i];
    float4 a = o4[i][0], c = o4[i][1];
    mul4(a, inv); mul4(c, inv);
    const int r = qg * 4 + i;
    float4* op = (float4*)(O + ((long)(b * SEQ + bq + r) * NH + h) * HD + dg * 8);
    op[0] = a; op[1] = c;
  }
}

// ---------------------------------------------------------------------------
extern "C" void kernel_launch(void* const* d_in, const int* in_sizes, int n_in,
                              void* d_out, int out_size, void* d_ws, size_t ws_size,
                              hipStream_t stream) {
  const float* x  = (const float*)d_in[0];
  const float* wq = (const float*)d_in[1];
  const float* wk = (const float*)d_in[2];
  const float* wv = (const float*)d_in[3];
  const float* wo = (const float*)d_in[4];
  float* out = (float*)d_out;

  const long T = (long)BATCH * SEQ;  // 4096 tokens

  float* Q   = (float*)d_ws;                 // T x DIM   (64 MB)
  float* Kb  = Q   + T * DIM;                // T x KVDIM (16 MB)
  float* Vb  = Kb  + T * KVDIM;              // T x KVDIM (16 MB)
  float* Ctx = Vb  + T * KVDIM;              // T x DIM   (64 MB)

  dim3 blk(256);
  sgemm_kernel<<<dim3(T / 128, DIM / 128),   blk, 0, stream>>>(x, wq, Q,  (int)T, DIM,   DIM);
  sgemm_kernel<<<dim3(T / 128, KVDIM / 128), blk, 0, stream>>>(x, wk, Kb, (int)T, KVDIM, DIM);
  sgemm_kernel<<<dim3(T / 128, KVDIM / 128), blk, 0, stream>>>(x, wv, Vb, (int)T, KVDIM, DIM);
  attn_kernel<<<dim3(BATCH * NH * (SEQ / QT)), blk, 0, stream>>>(Q, Kb, Vb, Ctx);
  sgemm_kernel<<<dim3(T / 128, DIM / 128),   blk, 0, stream>>>(Ctx, wo, out, (int)T, DIM, DIM);
}

// Round 4
// 4218.602 us; speedup vs baseline: 6.1643x; 1.6917x over previous
//
#include <hip/hip_runtime.h>
#include <hip/hip_bf16.h>

// Problem constants: B=2, S=2048, dim=4096, H=32, HKV=8, HD=128
#define BATCH 2
#define SEQ   2048
#define DIM   4096
#define KVDIM 1024
#define NH    32
#define NKVH  8
#define HD    128

#define QT 64   // q rows per attention block
#define KT 32   // keys per attention tile

typedef __attribute__((ext_vector_type(8))) short bf16x8_t;  // 8 bf16 (4 VGPR)
typedef __attribute__((ext_vector_type(4))) short short4_t;  // 8 B
typedef __attribute__((ext_vector_type(4))) float f32x4;

#define MFMA16(a, b, c) __builtin_amdgcn_mfma_f32_16x16x32_bf16(a, b, c, 0, 0, 0)

__device__ __forceinline__ unsigned short f2bf(float f) {   // RNE f32 -> bf16 bits
  unsigned u = __float_as_uint(f);
  u += 0x7fff + ((u >> 16) & 1);
  return (unsigned short)(u >> 16);
}
__device__ __forceinline__ float bf2f(unsigned short b) {
  return __uint_as_float((unsigned)b << 16);
}

// ---------------------------------------------------------------------------
// W[K][N] f32 -> transposed split Th/Tl [N][K] bf16. 32x32 tiles.
// ---------------------------------------------------------------------------
__global__ __launch_bounds__(256) void wsplit_t_kernel(
    const float* __restrict__ W, short* __restrict__ Th, short* __restrict__ Tl,
    int K, int N) {
  __shared__ float tile[32][33];
  const int t  = threadIdx.x;
  const int tx = t & 31, ty = t >> 5;      // ty 0..7
  const int k0 = blockIdx.x * 32, n0 = blockIdx.y * 32;
#pragma unroll
  for (int i = 0; i < 4; ++i)
    tile[ty + 8 * i][tx] = W[(long)(k0 + ty + 8 * i) * N + n0 + tx];
  __syncthreads();
#pragma unroll
  for (int i = 0; i < 4; ++i) {
    const float v = tile[tx][ty + 8 * i];
    const unsigned short hb = f2bf(v);
    const unsigned short lb = f2bf(v - bf2f(hb));
    const long o = (long)(n0 + ty + 8 * i) * K + k0 + tx;
    Th[o] = (short)hb;
    Tl[o] = (short)lb;
  }
}

// ---------------------------------------------------------------------------
// Split-bf16 MFMA GEMM:  C[M,N] f32 = A[M,K](f32, split in-kernel) @ B,
// where B is supplied pre-split & transposed: BTh/BTl [N][K] bf16.
// 128x128 tile, BK=32, 256 thr = 4 waves (2x2 of 64x64 sub-tiles).
// LDS slot swizzle: chunk c of row r stored at slot c ^ (r&3) ^ ((r>>2)&3)
//   -> fragment ds_read_b128 and staging writes are <=2-way (free, m136).
// Per K-step per wave: 16 ds_read_b128 + 48 MFMA (hh, hl, lh terms).
// ---------------------------------------------------------------------------
__global__ __launch_bounds__(256) void gemm_asplit_kernel(
    const float* __restrict__ A, const short* __restrict__ BTh,
    const short* __restrict__ BTl, float* __restrict__ C,
    int M, int N, int K) {
  __shared__ short Ah[128 * 32], Al[128 * 32], Bh[128 * 32], Bl[128 * 32];  // 32 KB

  const int t    = threadIdx.x;
  const int wid  = t >> 6;
  const int lane = t & 63;
  const int r16  = lane & 15;
  const int g    = lane >> 4;
  const int bm   = blockIdx.x * 128;
  const int bn   = blockIdx.y * 128;
  const int wm   = (wid >> 1) * 64;
  const int wn   = (wid & 1) * 64;

  // A staging: 128 rows x 8 float4; thread handles rows ar+32i, float4-col aq
  const int ar = t >> 3;          // 0..31
  const int aq = t & 7;           // 0..7
  // B staging: 128 rows x 4 chunks(16B); rows br+64i, chunk bc
  const int br = t >> 2;          // 0..63
  const int bc = t & 3;           // 0..3

  const float* Ag  = A   + (long)bm * K;
  const short* BhG = BTh + (long)bn * K;
  const short* BlG = BTl + (long)bn * K;

  f32x4 acc[4][4] = {};

  float4   areg[4];
  bf16x8_t bhreg[2], blreg[2];

#define LOADA(KT_)                                                        \
  {                                                                       \
    _Pragma("unroll") for (int i = 0; i < 4; ++i)                         \
        areg[i] = *(const float4*)&Ag[(long)(ar + 32 * i) * K + (KT_) + aq * 4]; \
  }
#define LOADB(KT_)                                                        \
  {                                                                       \
    _Pragma("unroll") for (int i = 0; i < 2; ++i) {                       \
      const long o = (long)(br + 64 * i) * K + (KT_) + bc * 8;            \
      bhreg[i] = *(const bf16x8_t*)&BhG[o];                               \
      blreg[i] = *(const bf16x8_t*)&BlG[o];                               \
    }                                                                     \
  }

  LOADA(0);
  LOADB(0);

  for (int kt = 0; kt < K; kt += 32) {
    __syncthreads();   // previous K-step's fragment reads complete

    // stage A (convert f32 -> bf16 hi/lo), swizzled
#pragma unroll
    for (int i = 0; i < 4; ++i) {
      const int r   = ar + 32 * i;
      const int s   = (aq >> 1) ^ (r & 3) ^ ((r >> 2) & 3);
      const int off = r * 32 + s * 8 + (aq & 1) * 4;
      const float4 v = areg[i];
      const unsigned short h0 = f2bf(v.x), h1 = f2bf(v.y),
                           h2 = f2bf(v.z), h3 = f2bf(v.w);
      short4_t hv = {(short)h0, (short)h1, (short)h2, (short)h3};
      short4_t lv = {(short)f2bf(v.x - bf2f(h0)), (short)f2bf(v.y - bf2f(h1)),
                     (short)f2bf(v.z - bf2f(h2)), (short)f2bf(v.w - bf2f(h3))};
      *(short4_t*)&Ah[off] = hv;
      *(short4_t*)&Al[off] = lv;
    }
    // stage B (already bf16), swizzled
#pragma unroll
    for (int i = 0; i < 2; ++i) {
      const int r   = br + 64 * i;
      const int s   = bc ^ (r & 3) ^ ((r >> 2) & 3);
      const int off = r * 32 + s * 8;
      *(bf16x8_t*)&Bh[off] = bhreg[i];
      *(bf16x8_t*)&Bl[off] = blreg[i];
    }
    __syncthreads();   // tile staged

    if (kt + 32 < K) {   // prefetch next tile, overlapped with MFMA
      LOADA(kt + 32);
      LOADB(kt + 32);
    }

    bf16x8_t ah[4], al[4], bh[4], bl[4];
#pragma unroll
    for (int f = 0; f < 4; ++f) {
      const int ma = wm + f * 16 + r16;
      const int sa = (g ^ (ma & 3) ^ ((ma >> 2) & 3)) * 8;
      ah[f] = *(const bf16x8_t*)&Ah[ma * 32 + sa];
      al[f] = *(const bf16x8_t*)&Al[ma * 32 + sa];
      const int nb = wn + f * 16 + r16;
      const int sb = (g ^ (nb & 3) ^ ((nb >> 2) & 3)) * 8;
      bh[f] = *(const bf16x8_t*)&Bh[nb * 32 + sb];
      bl[f] = *(const bf16x8_t*)&Bl[nb * 32 + sb];
    }
#pragma unroll
    for (int i = 0; i < 4; ++i)
#pragma unroll
      for (int j = 0; j < 4; ++j) {
        acc[i][j] = MFMA16(ah[i], bh[j], acc[i][j]);
        acc[i][j] = MFMA16(ah[i], bl[j], acc[i][j]);
        acc[i][j] = MFMA16(al[i], bh[j], acc[i][j]);
      }
  }

  // C/D layout (m89-verified): col = lane&15, row = (lane>>4)*4 + reg
#pragma unroll
  for (int i = 0; i < 4; ++i) {
    const int row0 = bm + wm + i * 16 + g * 4;
#pragma unroll
    for (int j = 0; j < 4; ++j) {
      const int col = bn + wn + j * 16 + r16;
      float* cp = C + (long)row0 * N + col;
#pragma unroll
      for (int r = 0; r < 4; ++r) cp[(long)r * N] = acc[i][j][r];
    }
  }
#undef LOADA
#undef LOADB
}

// ---------------------------------------------------------------------------
// Flash attention, fp32. O may alias Q (in-place): each block fully stages its
// own Q tile into LDS before writing the same locations in the epilogue.
// ---------------------------------------------------------------------------
__device__ __forceinline__ void fma4(float4& a, float s, const float4& v) {
  a.x = fmaf(s, v.x, a.x); a.y = fmaf(s, v.y, a.y);
  a.z = fmaf(s, v.z, a.z); a.w = fmaf(s, v.w, a.w);
}
__device__ __forceinline__ void mul4(float4& a, float s) {
  a.x *= s; a.y *= s; a.z *= s; a.w *= s;
}

__global__ __launch_bounds__(256) void attn_kernel(
    const float* Q, const float* __restrict__ Kb,
    const float* __restrict__ Vb, float* O) {
  __shared__ float4 Qs[QT * 32];    // [r][c4 ^ (r&7)]          32 KB
  __shared__ float4 KPs[KT * 32];   // K: [k][c4 ^ ((k>>1)&7)]  16 KB; later P^T
  __shared__ float4 Vs[KT * 32];    // [k][c4 ^ ((k>>1)&7)]     16 KB

  float* Pt = (float*)KPs;          // P^T row stride 68 floats (17 f4)

  const int t  = threadIdx.x;
  const int qg = t >> 4;            // 0..15 -> q rows qg*4+i
  const int kg = t & 15;            // S phase: k cols kg*2+jj
  const int dg = t & 15;            // PV phase: d cols dg*8

  const int tile = blockIdx.x & 31;
  const int h    = (blockIdx.x >> 5) & 31;
  const int b    = blockIdx.x >> 10;
  const int bq   = tile * QT;
  const int hkv  = h >> 2;          // repeat_interleave, n_rep=4

  const float4* Qg = (const float4*)(Q + ((long)(b * SEQ + bq) * NH + h) * HD);
  const float4* Kg = (const float4*)(Kb + (long)b * SEQ * KVDIM + hkv * HD);
  const float4* Vg = (const float4*)(Vb + (long)b * SEQ * KVDIM + hkv * HD);

  const int pr_ = t >> 5;   // row group 0..7
  const int ps_ = t & 31;   // slot 0..31

  // ---- stage Q tile (conflict-free: one full 512B row per half-wave) ----
#pragma unroll
  for (int j = 0; j < 8; ++j) {
    const int r = pr_ + 8 * j;
    Qs[r * 32 + (ps_ ^ (r & 7))] = Qg[(long)r * (DIM / 4) + ps_];
  }

  // ---- prefetch K/V tile 0 ----
  float4 kreg[4], vreg[4];
#pragma unroll
  for (int j = 0; j < 4; ++j) {
    const int r = pr_ + 8 * j;
    kreg[j] = Kg[(long)r * (KVDIM / 4) + ps_];
    vreg[j] = Vg[(long)r * (KVDIM / 4) + ps_];
  }

  float4 o4[4][2] = {};
  float m[4] = {-INFINITY, -INFINITY, -INFINITY, -INFINITY};
  float l[4] = {0.f, 0.f, 0.f, 0.f};

  const int NT = SEQ / KT;           // 64
  for (int kt = 0; kt < NT; ++kt) {
#pragma unroll
    for (int j = 0; j < 4; ++j) {
      const int r  = pr_ + 8 * j;
      const int sw = r * 32 + (ps_ ^ ((r >> 1) & 7));
      KPs[sw] = kreg[j];
      Vs [sw] = vreg[j];
    }
    __syncthreads();   // #1 tile ready

    if (kt + 1 < NT) {
      const long rb = (long)((kt + 1) * KT);
#pragma unroll
      for (int j = 0; j < 4; ++j) {
        const int r = pr_ + 8 * j;
        kreg[j] = Kg[(rb + r) * (KVDIM / 4) + ps_];
        vreg[j] = Vg[(rb + r) * (KVDIM / 4) + ps_];
      }
    }

    // ---- S = Q K^T : 4 q x 2 k per thread ----
    float s[4][2] = {};
    const int k0 = kg * 2, k1 = k0 + 1;
    const int fk = kg & 7;           // (k0>>1)&7
#pragma unroll
    for (int d4 = 0; d4 < 32; ++d4) {
      const float4 kv0 = KPs[k0 * 32 + (d4 ^ fk)];
      const float4 kv1 = KPs[k1 * 32 + (d4 ^ fk)];
#pragma unroll
      for (int i = 0; i < 4; ++i) {
        const int r = qg * 4 + i;
        const float4 qv = Qs[r * 32 + (d4 ^ (r & 7))];
        s[i][0] += qv.x * kv0.x + qv.y * kv0.y + qv.z * kv0.z + qv.w * kv0.w;
        s[i][1] += qv.x * kv1.x + qv.y * kv1.y + qv.z * kv1.z + qv.w * kv1.w;
      }
    }

    // ---- online softmax (16-lane groups) ----
    const float scale = 0.08838834764831845f;
    float pr[4][2];
#pragma unroll
    for (int i = 0; i < 4; ++i) {
      const float s0 = s[i][0] * scale, s1 = s[i][1] * scale;
      float mt = fmaxf(s0, s1);
      mt = fmaxf(mt, __shfl_xor(mt, 1));
      mt = fmaxf(mt, __shfl_xor(mt, 2));
      mt = fmaxf(mt, __shfl_xor(mt, 4));
      mt = fmaxf(mt, __shfl_xor(mt, 8));
      const float mn  = fmaxf(m[i], mt);
      const float cor = __expf(m[i] - mn);
      m[i] = mn;
      const float p0 = __expf(s0 - mn), p1 = __expf(s1 - mn);
      pr[i][0] = p0; pr[i][1] = p1;
      float rs = p0 + p1;
      rs += __shfl_xor(rs, 1);
      rs += __shfl_xor(rs, 2);
      rs += __shfl_xor(rs, 4);
      rs += __shfl_xor(rs, 8);
      l[i] = l[i] * cor + rs;
      mul4(o4[i][0], cor);
      mul4(o4[i][1], cor);
    }
    __syncthreads();   // #2 K reads done

    // write P^T as float4 per k (q's contiguous)
    ((float4*)Pt)[k0 * 17 + qg] = make_float4(pr[0][0], pr[1][0], pr[2][0], pr[3][0]);
    ((float4*)Pt)[k1 * 17 + qg] = make_float4(pr[0][1], pr[1][1], pr[2][1], pr[3][1]);
    __syncthreads();   // #3 P^T visible

    // ---- O += P V : 4 q x 8 d per thread ----
#pragma unroll 8
    for (int k = 0; k < KT; ++k) {
      const float4 p4 = ((const float4*)Pt)[k * 17 + qg];
      const int fv = (k >> 1) & 7;
      const float4 v0 = Vs[k * 32 + ((dg * 2)     ^ fv)];
      const float4 v1 = Vs[k * 32 + ((dg * 2 + 1) ^ fv)];
      fma4(o4[0][0], p4.x, v0); fma4(o4[0][1], p4.x, v1);
      fma4(o4[1][0], p4.y, v0); fma4(o4[1][1], p4.y, v1);
      fma4(o4[2][0], p4.z, v0); fma4(o4[2][1], p4.z, v1);
      fma4(o4[3][0], p4.w, v0); fma4(o4[3][1], p4.w, v1);
    }
    __syncthreads();   // #4 PV reads done
  }

#pragma unroll
  for (int i = 0; i < 4; ++i) {
    const float inv = 1.0f / l[i];
    float4 a = o4[i][0], c = o4[i][1];
    mul4(a, inv); mul4(c, inv);
    const int r = qg * 4 + i;
    float4* op = (float4*)(O + ((long)(b * SEQ + bq + r) * NH + h) * HD + dg * 8);
    op[0] = a; op[1] = c;
  }
}

// ---------------------------------------------------------------------------
// Workspace (exactly 160 MiB, the r2-proven footprint):
//   wTh, wTl : 32 MiB each (reused for wq, wk, wv, wo sequentially)
//   Q        : 64 MiB f32  (attn output written in-place)
//   Kb, Vb   : 16 MiB each
// ---------------------------------------------------------------------------
extern "C" void kernel_launch(void* const* d_in, const int* in_sizes, int n_in,
                              void* d_out, int out_size, void* d_ws, size_t ws_size,
                              hipStream_t stream) {
  const float* x  = (const float*)d_in[0];
  const float* wq = (const float*)d_in[1];
  const float* wk = (const float*)d_in[2];
  const float* wv = (const float*)d_in[3];
  const float* wo = (const float*)d_in[4];
  float* out = (float*)d_out;

  const long T = (long)BATCH * SEQ;           // 4096 tokens

  char* w = (char*)d_ws;
  auto alloc = [&](size_t bytes) {
    char* p = w;
    w += (bytes + 255) & ~(size_t)255;
    return p;
  };
  short* wTh = (short*)alloc((long)DIM * DIM * 2);   // 32 MiB
  short* wTl = (short*)alloc((long)DIM * DIM * 2);   // 32 MiB
  float* Q   = (float*)alloc(T * DIM * 4);           // 64 MiB (also attn out)
  float* Kb  = (float*)alloc(T * KVDIM * 4);         // 16 MiB
  float* Vb  = (float*)alloc(T * KVDIM * 4);         // 16 MiB

  dim3 blk(256);

  // Q projection
  wsplit_t_kernel<<<dim3(DIM / 32, DIM / 32), blk, 0, stream>>>(wq, wTh, wTl, DIM, DIM);
  gemm_asplit_kernel<<<dim3(T / 128, DIM / 128), blk, 0, stream>>>(
      x, wTh, wTl, Q, (int)T, DIM, DIM);
  // K projection
  wsplit_t_kernel<<<dim3(DIM / 32, KVDIM / 32), blk, 0, stream>>>(wk, wTh, wTl, DIM, KVDIM);
  gemm_asplit_kernel<<<dim3(T / 128, KVDIM / 128), blk, 0, stream>>>(
      x, wTh, wTl, Kb, (int)T, KVDIM, DIM);
  // V projection
  wsplit_t_kernel<<<dim3(DIM / 32, KVDIM / 32), blk, 0, stream>>>(wv, wTh, wTl, DIM, KVDIM);
  gemm_asplit_kernel<<<dim3(T / 128, KVDIM / 128), blk, 0, stream>>>(
      x, wTh, wTl, Vb, (int)T, KVDIM, DIM);

  // attention (writes output in-place over Q)
  attn_kernel<<<dim3(BATCH * NH * (SEQ / QT)), blk, 0, stream>>>(Q, Kb, Vb, Q);

  // output projection
  wsplit_t_kernel<<<dim3(DIM / 32, DIM / 32), blk, 0, stream>>>(wo, wTh, wTl, DIM, DIM);
  gemm_asplit_kernel<<<dim3(T / 128, DIM / 128), blk, 0, stream>>>(
      Q, wTh, wTl, out, (int)T, DIM, DIM);
}